// Round 24
// baseline (811.929 us; speedup 1.0000x reference)
//
#include <hip/hip_runtime.h>
#include <cstdint>

namespace {

typedef _Float16 f16_t;
typedef _Float16 f16x8 __attribute__((ext_vector_type(8)));
typedef _Float16 f16x4 __attribute__((ext_vector_type(4)));
typedef float    f32x4 __attribute__((ext_vector_type(4)));
typedef float    f32x16 __attribute__((ext_vector_type(16)));

constexpr int Bc = 4, Tc = 1024, Hc = 4, Dc = 256, DHc = 1024, Lc = 6, Vc = 256;
constexpr int HALFc = 512;
constexpr float EPS = 1e-5f;
constexpr long long T4q  = (long long)Tc * 4096;      // 4M (row stride of xr per b)
constexpr long long TDq  = (long long)Tc * Dc;        // 256K
constexpr long long HDDq = (long long)DHc * Dc;       // 256K
constexpr long long TBUFq = (long long)Bc * Tc * Dc;  // 1M (split-K slice elems)

// Interleaved-pair permutation of the Dh axis: e -> 2*(e%512) + (e/512).
// RoPE pairs are adjacent he columns -> adjacent lanes in MFMA C/D frags.
__device__ __forceinline__ int pe_perm(int v) {
  return (v & ~1023) | ((v & 511) << 1) | ((v >> 9) & 1);
}

__device__ __forceinline__ void gload16(const void* g, void* l) {
  __builtin_amdgcn_global_load_lds((const __attribute__((address_space(1))) void*)g,
                                   (__attribute__((address_space(3))) void*)l, 16, 0, 0);
}

// LDS 16B-slot swizzle (r16): slot(k,r) = (k>>3) ^ (r&7) ^ ((r>>3)&7).

// k-major operand staging (r16-coalesced). NW=16: f16x4 loads.
template<int NW>
__device__ __forceinline__ void stage_kmaj(const f16_t* __restrict__ P, int k0,
                                           int ld, int c0, f16_t* S, int tid) {
  if constexpr (NW == 16) {
    const int cg = tid & 15;
    const int kp = (tid >> 4) & 31;
    const int jh = (tid >> 9) * 4;
    const int k  = kp * 2;
    const f16x4 r0 = *(const f16x4*)(P + (size_t)(k0 + k) * ld + c0 + cg * 8 + jh);
    const f16x4 r1 = *(const f16x4*)(P + (size_t)(k0 + k + 1) * ld + c0 + cg * 8 + jh);
    #pragma unroll
    for (int j = 0; j < 4; ++j) {
      const int n = cg * 8 + jh + j;
      union { f16_t h[2]; unsigned int u; } pk;
      pk.h[0] = r0[j]; pk.h[1] = r1[j];
      ((unsigned int*)S)[n * 32 + ((((kp >> 2) ^ (n & 7) ^ ((n >> 3) & 7)) & 7) << 2)
                         + (kp & 3)] = pk.u;
    }
  } else {
    const int cg  = tid & 15;
    const int kpb = tid >> 4;
    constexpr int NP = (NW == 4) ? 2 : 1;
    #pragma unroll
    for (int p = 0; p < NP; ++p) {
      const int kp = p * 16 + kpb;
      const int k  = kp * 2;
      const f16x8 r0 = *(const f16x8*)(P + (size_t)(k0 + k) * ld + c0 + cg * 8);
      const f16x8 r1 = *(const f16x8*)(P + (size_t)(k0 + k + 1) * ld + c0 + cg * 8);
      #pragma unroll
      for (int j = 0; j < 8; ++j) {
        const int n = cg * 8 + j;
        union { f16_t h[2]; unsigned int u; } pk;
        pk.h[0] = r0[j]; pk.h[1] = r1[j];
        ((unsigned int*)S)[n * 32 + ((((kp >> 2) ^ (n & 7) ^ ((n >> 3) & 7)) & 7) << 2)
                           + (kp & 3)] = pk.u;
      }
    }
  }
}

// ---------------------------------------------------------------------------
// MFMA f16 GEMM (r23 state): 128x128 tile, BK=64, 32x32x16 MFMA, KU unroll,
// GRPZ z-grouping (r22 win). Used for gemm1/3/4/readout.
// ---------------------------------------------------------------------------
template<int EPI, bool AKMAJ, bool BKMAJ, int NW, int KU, bool GRPZ>
__global__ __launch_bounds__(NW * 64)
void gemm_f16(const f16_t* __restrict__ A, long long sAb, long long sAh,
              const f16_t* __restrict__ B, long long sBb, long long sBh,
              void* __restrict__ Cv, long long sCb, long long sCh,
              const f16_t* __restrict__ aux,
              int K, int lda, int ldb, int ldc,
              const float* __restrict__ cosP, const float* __restrict__ sinP)
{
  constexpr int FN2  = (NW == 4) ? 2 : 1;
  constexpr int MT   = (NW == 16) ? 1 : 2;
  constexpr int WCW  = FN2 * 32;
  constexpr int WRH  = MT * 32;
  constexpr int NTHR = NW * 64;
  constexpr int SP   = 1024 / NTHR;
  constexpr int RPP  = NTHR / 8;

  __shared__ __align__(16) f16_t As[KU][128 * 64];
  __shared__ __align__(16) f16_t Bs[KU][128 * 64];

  int bx = blockIdx.x, by = blockIdx.y, bz = blockIdx.z;
  if (GRPZ) {
    const int Xd = gridDim.x, Zd = gridDim.z;
    const int f  = blockIdx.x + Xd * (blockIdx.y + gridDim.y * blockIdx.z);
    bz = f % Zd;
    const int rem = f / Zd;
    bx = rem % Xd;
    by = rem / Xd;
  }

  const int zb = bz >> 2, zh = bz & 3;
  A += zb * sAb + zh * sAh;
  B += zb * sBb + zh * sBh;
  const long long Coff = zb * sCb + zh * sCh;

  const int tid  = threadIdx.x;
  const int lane = tid & 63;
  const int wave = tid >> 6;
  const int wr = (NW == 4) ? (wave >> 1) : (wave >> 2);
  const int wc = (NW == 4) ? (wave & 1)  : (wave & 3);
  const int m0 = by * 128, n0 = bx * 128;

  const int lrow  = tid >> 3;
  const int lslot = tid & 7;

  f32x16 acc[MT][FN2] = {};

  for (int k0 = 0; k0 < K; k0 += KU * 64) {
    #pragma unroll
    for (int u = 0; u < KU; ++u) {
      const int ku = k0 + u * 64;
      if (!AKMAJ) {
        #pragma unroll
        for (int c = 0; c < SP; ++c) {
          const int row  = c * RPP + lrow;
          const int scol = ((lslot ^ (row & 7) ^ ((row >> 3) & 7)) << 3);
          gload16(A + (size_t)(m0 + row) * lda + ku + scol, &As[u][(c * NTHR + tid) * 8]);
        }
      } else {
        stage_kmaj<NW>(A, ku, lda, m0, As[u], tid);
      }
      if (!BKMAJ) {
        #pragma unroll
        for (int c = 0; c < SP; ++c) {
          const int row  = c * RPP + lrow;
          const int scol = ((lslot ^ (row & 7) ^ ((row >> 3) & 7)) << 3);
          gload16(B + (size_t)(n0 + row) * ldb + ku + scol, &Bs[u][(c * NTHR + tid) * 8]);
        }
      } else {
        stage_kmaj<NW>(B, ku, ldb, n0, Bs[u], tid);
      }
    }
    __syncthreads();

    #pragma unroll
    for (int u = 0; u < KU; ++u) {
      #pragma unroll
      for (int kc = 0; kc < 4; ++kc) {
        f16x8 af[MT], bf[FN2];
        #pragma unroll
        for (int m = 0; m < MT; ++m) {
          const int r  = wr * WRH + m * 32 + (lane & 31);
          const int sl = (kc * 2 + (lane >> 5)) ^ (r & 7) ^ ((r >> 3) & 7);
          af[m] = *(const f16x8*)(&As[u][r * 64 + sl * 8]);
        }
        #pragma unroll
        for (int n = 0; n < FN2; ++n) {
          const int r  = wc * WCW + n * 32 + (lane & 31);
          const int sl = (kc * 2 + (lane >> 5)) ^ (r & 7) ^ ((r >> 3) & 7);
          bf[n] = *(const f16x8*)(&Bs[u][r * 64 + sl * 8]);
        }
        #pragma unroll
        for (int m = 0; m < MT; ++m)
          #pragma unroll
          for (int n = 0; n < FN2; ++n)
            acc[m][n] = __builtin_amdgcn_mfma_f32_32x32x16_f16(af[m], bf[n], acc[m][n], 0, 0, 0);
      }
    }
    __syncthreads();
  }

  const int rbase = 4 * (lane >> 5);
  if (EPI == 4) {
    float* C = (float*)Cv + Coff;
    #pragma unroll
    for (int m = 0; m < MT; ++m)
      #pragma unroll
      for (int n = 0; n < FN2; ++n) {
        const int gcol = n0 + wc * WCW + n * 32 + (lane & 31);
        #pragma unroll
        for (int reg = 0; reg < 16; ++reg) {
          const int grow = m0 + wr * WRH + m * 32 + (reg & 3) + 8 * (reg >> 2) + rbase;
          C[(long long)grow * ldc + gcol] = acc[m][n][reg];
        }
      }
  } else if (EPI == 5) {
    // xr = RoPE(relu(acc)); pair partner in adjacent lane
    f16_t* C = (f16_t*)Cv + Coff;
    #pragma unroll
    for (int m = 0; m < MT; ++m)
      #pragma unroll
      for (int n = 0; n < FN2; ++n) {
        const int gcol = n0 + wc * WCW + n * 32 + (lane & 31);
        const int jj   = (gcol & 1023) >> 1;
        const float sg = (gcol & 1) ? 1.0f : -1.0f;
        #pragma unroll
        for (int reg = 0; reg < 16; ++reg) {
          const int grow = m0 + wr * WRH + m * 32 + (reg & 3) + 8 * (reg >> 2) + rbase;
          const int tt   = grow & (Tc - 1);
          const float val  = fmaxf(acc[m][n][reg], 0.0f);
          const float part = __shfl_xor(val, 1);
          const float c = cosP[tt * HALFc + jj];
          const float s = sinP[tt * HALFc + jj];
          C[(long long)grow * ldc + gcol] = (f16_t)(val * c + part * s * sg);
        }
      }
  } else {
    f16_t* C = (f16_t*)Cv + Coff;
    #pragma unroll
    for (int m = 0; m < MT; ++m)
      #pragma unroll
      for (int n = 0; n < FN2; ++n) {
        const int gcol = n0 + wc * WCW + n * 32 + (lane & 31);
        #pragma unroll
        for (int reg = 0; reg < 16; ++reg) {
          const int grow = m0 + wr * WRH + m * 32 + (reg & 3) + 8 * (reg >> 2) + rbase;
          C[(long long)grow * ldc + gcol] = (f16_t)acc[m][n][reg];
        }
      }
  }
}

// ---------------------------------------------------------------------------
// r24: FUSED gemm5+gemm6 — eliminates the yb tensor (64 MB/layer round-trip).
// Grid (32 bt-blocks, 1, 8 z = h*2+half), 1024 thr (16 waves, 4x4 of 32x32).
// Per block: t_slice[128 bt][256 d] (acc [2] f32x16/lane) accumulated over
// 4 he-blocks of 128 within (h, half):
//   stage1 (K=256, 4 steps): y_sub = relu(a_tile . DyT_sub^T)  (yacc f32x16)
//   epilogue1: y = y_sub * invRoPE(xr) per-lane -> swizzled LDS As2[2]
//              ([128 bt rows][64 he-k] x2, r16 slot fn; bank-checked 2-way)
//   stage2 (K=128, 2 steps): t_acc += y . ET_sub^T (ET rows 0..255 in Bs2[2])
// Final: t_slice stored f16 (r20). GRPZ grouping (shared DyT/ET panels).
// LDS: 16+16+32+32 = 96 KB -> 1 block/CU, 4 waves/SIMD.
// ---------------------------------------------------------------------------
__global__ __launch_bounds__(1024)
void gemm56(const f16_t* __restrict__ a,     // [B*T][H*D]
            const f16_t* __restrict__ DyT,   // [4096 he][256] (perm rows)
            const f16_t* __restrict__ xr,    // [B*T][4096]
            const f16_t* __restrict__ ET,    // [256][4096] (perm cols)
            f16_t* __restrict__ t,           // 8 slices of [B*T][256]
            const float* __restrict__ cosP, const float* __restrict__ sinP)
{
  __shared__ __align__(16) f16_t As1[128 * 64];      // a-tile
  __shared__ __align__(16) f16_t Bs1[128 * 64];      // DyT-tile
  __shared__ __align__(16) f16_t As2[2][128 * 64];   // y (k = he, 2x64)
  __shared__ __align__(16) f16_t Bs2[2][128 * 64];   // ET rows 0..255

  // GRPZ remap: co-locate same-z blocks (shared DyT/ET panels)
  const int f  = blockIdx.x + 32 * blockIdx.z;
  const int bz = f & 7;            // z = h*2 + half
  const int bx = f >> 3;           // bt-block
  const int h = bz >> 1, half = bz & 1;
  const int m0 = bx * 128;

  const int tid  = threadIdx.x;
  const int lane = tid & 63;
  const int wave = tid >> 6;
  const int wr = wave >> 2, wc = wave & 3;
  const int lrow  = tid >> 3;       // 0..127
  const int lslot = tid & 7;
  const int rbase = 4 * (lane >> 5);

  f32x16 tacc[2] = {};              // d = wc*64 + n*32 + (lane&31)

  for (int hb = 0; hb < 4; ++hb) {
    const int he0 = h * 1024 + half * 512 + hb * 128;  // global he base

    // ---- stage1: yacc = a_tile . DyT_sub^T  (K = 256) ----
    f32x16 yacc = {};
    for (int k0 = 0; k0 < 256; k0 += 64) {
      const int scol = ((lslot ^ (lrow & 7) ^ ((lrow >> 3) & 7)) << 3);
      gload16(a + (size_t)(m0 + lrow) * 1024 + h * 256 + k0 + scol, &As1[tid * 8]);
      gload16(DyT + (size_t)(he0 + lrow) * 256 + k0 + scol, &Bs1[tid * 8]);
      __syncthreads();
      #pragma unroll
      for (int kc = 0; kc < 4; ++kc) {
        const int rA  = wr * 32 + (lane & 31);
        const int slA = (kc * 2 + (lane >> 5)) ^ (rA & 7) ^ ((rA >> 3) & 7);
        const f16x8 af = *(const f16x8*)(&As1[rA * 64 + slA * 8]);
        const int rB  = wc * 32 + (lane & 31);
        const int slB = (kc * 2 + (lane >> 5)) ^ (rB & 7) ^ ((rB >> 3) & 7);
        const f16x8 bf = *(const f16x8*)(&Bs1[rB * 64 + slB * 8]);
        yacc = __builtin_amdgcn_mfma_f32_32x32x16_f16(af, bf, yacc, 0, 0, 0);
      }
      __syncthreads();
    }

    // ---- epilogue1: y = relu(yacc) * invRoPE(xr) -> As2 (swizzled) ----
    {
      const int heL  = wc * 32 + (lane & 31);     // local he 0..127
      const int gcol = he0 + heL;                 // global he
      const int jj   = (gcol & 1023) >> 1;
      const float sg = (gcol & 1) ? 1.0f : -1.0f;
      const int kk   = heL & 63;
      const int buf  = heL >> 6;
      #pragma unroll
      for (int reg = 0; reg < 16; ++reg) {
        const int rowL = wr * 32 + (reg & 3) + 8 * (reg >> 2) + rbase;  // bt local
        const int grow = m0 + rowL;
        const int tt   = grow & (Tc - 1);
        const float xrv  = (float)xr[(size_t)grow * 4096 + gcol];
        const float part = __shfl_xor(xrv, 1);
        const float c = cosP[tt * HALFc + jj];
        const float s = sinP[tt * HALFc + jj];
        const float xv = xrv * c - part * s * sg;
        const float yv = fmaxf(yacc[reg], 0.0f) * xv;
        const int sl = (kk >> 3) ^ (rowL & 7) ^ ((rowL >> 3) & 7);
        As2[buf][rowL * 64 + sl * 8 + (kk & 7)] = (f16_t)yv;
      }
    }
    __syncthreads();   // As2 complete before stage2 reads

    // ---- stage2: tacc += y . ET_sub^T  (K = 128, 2 steps of 64) ----
    #pragma unroll
    for (int ks2 = 0; ks2 < 2; ++ks2) {
      const int scol = ((lslot ^ (lrow & 7) ^ ((lrow >> 3) & 7)) << 3);
      gload16(ET + (size_t)lrow * 4096 + he0 + ks2 * 64 + scol, &Bs2[0][tid * 8]);
      gload16(ET + (size_t)(128 + lrow) * 4096 + he0 + ks2 * 64 + scol, &Bs2[1][tid * 8]);
      __syncthreads();
      #pragma unroll
      for (int kc = 0; kc < 4; ++kc) {
        const int rA  = wr * 32 + (lane & 31);
        const int slA = (kc * 2 + (lane >> 5)) ^ (rA & 7) ^ ((rA >> 3) & 7);
        const f16x8 af = *(const f16x8*)(&As2[ks2][rA * 64 + slA * 8]);
        #pragma unroll
        for (int n = 0; n < 2; ++n) {
          const int d    = wc * 64 + n * 32 + (lane & 31);
          const int rloc = d & 127;
          const int sl   = (kc * 2 + (lane >> 5)) ^ (rloc & 7) ^ ((rloc >> 3) & 7);
          const f16x8 bf = *(const f16x8*)(&Bs2[d >> 7][rloc * 64 + sl * 8]);
          tacc[n] = __builtin_amdgcn_mfma_f32_32x32x16_f16(af, bf, tacc[n], 0, 0, 0);
        }
      }
      __syncthreads();
    }
  }

  // ---- final: t slice (f16, EPI=0 style) ----
  f16_t* T = t + (long long)bz * TBUFq;
  #pragma unroll
  for (int n = 0; n < 2; ++n) {
    const int gcol = wc * 64 + n * 32 + (lane & 31);
    #pragma unroll
    for (int reg = 0; reg < 16; ++reg) {
      const int grow = m0 + wr * 32 + (reg & 3) + 8 * (reg >> 2) + rbase;
      T[(size_t)grow * 256 + gcol] = (f16_t)tacc[n][reg];
    }
  }
}

// fp32 [R][C] -> f16 [C][R], batched over z; perm applies pe_perm.
__global__ __launch_bounds__(256)
void transpose_f32_f16(const float* __restrict__ in, f16_t* __restrict__ out,
                       int R, int C, long long sIn, long long sOut,
                       int permR, int permC)
{
  __shared__ float tile[32][33];
  in  += (long long)blockIdx.z * sIn;
  out += (long long)blockIdx.z * sOut;
  const int c0 = blockIdx.x * 32, r0 = blockIdx.y * 32;
  const int tx = threadIdx.x & 31, ty = threadIdx.x >> 5;
  #pragma unroll
  for (int i = 0; i < 32; i += 8)
    tile[ty + i][tx] = in[(long long)(r0 + ty + i) * C + (c0 + tx)];
  __syncthreads();
  #pragma unroll
  for (int i = 0; i < 32; i += 8) {
    int ro = c0 + ty + i;
    int co = r0 + tx;
    if (permR) ro = pe_perm(ro);
    if (permC) co = pe_perm(co);
    out[(long long)ro * R + co] = (f16_t)tile[tx][ty + i];
  }
}

// cos/sin[t][j] = cos/sin(t * 10000^(-j/512))
__global__ __launch_bounds__(256)
void init_tables(float* __restrict__ cosT, float* __restrict__ sinT)
{
  const int i = blockIdx.x * 256 + threadIdx.x;
  const int j = i & (HALFc - 1);
  const int t = i >> 9;
  const float inv = expf(-(float)j * (9.210340371976184f / 512.0f));
  const float ang = (float)t * inv;
  cosT[i] = cosf(ang);
  sinT[i] = sinf(ang);
}

__device__ __forceinline__ void block_stats(float val, float* red, float& mean, float& inv_std)
{
  float s1 = val, s2 = val * val;
  #pragma unroll
  for (int o = 1; o < 64; o <<= 1) {
    s1 += __shfl_xor(s1, o);
    s2 += __shfl_xor(s2, o);
  }
  const int lane = threadIdx.x & 63;
  const int w = threadIdx.x >> 6;
  if (lane == 0) { red[w * 2] = s1; red[w * 2 + 1] = s2; }
  __syncthreads();
  s1 = red[0] + red[2] + red[4] + red[6];
  s2 = red[1] + red[3] + red[5] + red[7];
  mean = s1 * (1.0f / Dc);
  const float var = s2 * (1.0f / Dc) - mean * mean;
  inv_std = 1.0f / sqrtf(var + EPS);
  __syncthreads();
}

__global__ __launch_bounds__(256)
void embed_ln(const int* __restrict__ tokens, const float* __restrict__ emb,
              f16_t* __restrict__ v)
{
  __shared__ float red[8];
  const int row = blockIdx.x;
  const int d = threadIdx.x;
  const float val = emb[(long long)tokens[row] * Dc + d];
  float m, is;
  block_stats(val, red, m, is);
  v[(long long)row * Dc + d] = (f16_t)((val - m) * is);
}

// v = LN(v + LN(sum_{z<8} t_z)); t split-K slices f16 (r24: 8 slices)
__global__ __launch_bounds__(256)
void fuse_ln8(f16_t* __restrict__ v, const f16_t* __restrict__ t)
{
  __shared__ float red[8];
  const long long row = blockIdx.x;
  const int d = threadIdx.x;
  const long long off = row * Dc + d;
  float tv = 0.0f;
  #pragma unroll
  for (int s = 0; s < 8; ++s) tv += (float)t[off + s * TBUFq];
  float m1, is1;
  block_stats(tv, red, m1, is1);
  const float u = (tv - m1) * is1;
  const float wv = (float)v[off] + u;
  float m2, is2;
  block_stats(wv, red, m2, is2);
  v[off] = (f16_t)((wv - m2) * is2);
}

}  // anonymous namespace

extern "C" void kernel_launch(void* const* d_in, const int* in_sizes, int n_in,
                              void* d_out, int out_size, void* d_ws, size_t ws_size,
                              hipStream_t stream)
{
  (void)in_sizes; (void)n_in; (void)out_size; (void)ws_size;
  const int*   tokens  = (const int*)d_in[0];
  const float* emb_w   = (const float*)d_in[1];
  const float* E       = (const float*)d_in[2];
  const float* Dx      = (const float*)d_in[3];
  const float* Dy      = (const float*)d_in[4];
  const float* readout = (const float*)d_in[5];
  float* out = (float*)d_out;

  // Workspace carve-up (~80 MB)
  char* w = (char*)d_ws;
  auto carve = [&](size_t bytes) { char* p = w; w += (bytes + 255) & ~(size_t)255; return p; };
  float* cosT = (float*)carve((size_t)Tc * HALFc * 4);        // 2 MB
  float* sinT = (float*)carve((size_t)Tc * HALFc * 4);        // 2 MB
  f16_t* v    = (f16_t*)carve((size_t)Bc * Tc * Dc * 2);      // 2 MB
  f16_t* xr   = (f16_t*)carve((size_t)Bc * Tc * 4096 * 2);    // 32 MB [B*T][H*Dh]
  f16_t* WT   = (f16_t*)carve((size_t)Bc * Dc * 4096 * 2);    // 8 MB [B][D][H*Dh]
  f16_t* a    = (f16_t*)carve((size_t)Bc * Tc * Hc * Dc * 2); // 8 MB [B*T][H*D]
  f16_t* t    = (f16_t*)carve((size_t)8 * TBUFq * 2);         // 16 MB (8 f16 slices)
  f16_t* DxT  = (f16_t*)carve((size_t)Hc * DHc * Dc * 2);     // 2 MB (perm rows)
  f16_t* DyT  = (f16_t*)carve((size_t)Hc * DHc * Dc * 2);     // 2 MB (perm rows)
  f16_t* ET   = (f16_t*)carve((size_t)Dc * Hc * DHc * 2);     // 2 MB [D][he] (perm cols)
  f16_t* RT   = (f16_t*)carve((size_t)Vc * Dc * 2);           // 128 KB

  // One-time prep (weights carry the interleaved-pair he permutation)
  transpose_f32_f16<<<dim3(32, 8, Hc), 256, 0, stream>>>(Dx, DxT, Dc, DHc, HDDq, HDDq, 1, 0);
  transpose_f32_f16<<<dim3(32, 8, Hc), 256, 0, stream>>>(Dy, DyT, Dc, DHc, HDDq, HDDq, 1, 0);
  transpose_f32_f16<<<dim3(8, 128, 1), 256, 0, stream>>>(E, ET, 4096, Dc, 0, 0, 0, 1);
  transpose_f32_f16<<<dim3(8, 8, 1), 256, 0, stream>>>(readout, RT, Dc, Vc, 0, 0, 0, 0);
  init_tables<<<(Tc * HALFc) / 256, 256, 0, stream>>>(cosT, sinT);
  embed_ln<<<Bc * Tc, 256, 0, stream>>>(tokens, emb_w, v);

  for (int l = 0; l < Lc; ++l) {
    // 1) xr = RoPE(relu(v . DxT^T)): [4096 x 4096], K=256 — NW=8, KU=1
    gemm_f16<5, false, false, 8, 1, false><<<dim3(32, 32, 1), 512, 0, stream>>>(
        v, 0, 0, DxT, 0, 0, xr, 0, 0, nullptr, Dc, Dc, Dc, 4096, cosT, sinT);
    // 3) WT[b] = v_b^T . xr_b: [256 x 4096], K=1024, z=4 — NW=16, KU=2, GRPZ
    gemm_f16<0, true, true, 16, 2, true><<<dim3(32, 2, 4), 1024, 0, stream>>>(
        v, 0, TDq, xr, 0, T4q, WT, 0, (long long)Dc * 4096, nullptr,
        Tc, Dc, 4096, 4096, nullptr, nullptr);
    // 4) a[b,:,h,:] = xr_bh . WT_bh^T: [1024 x 256], K=1024, z=16 — NW=16, KU=2, GRPZ
    gemm_f16<0, false, false, 16, 2, true><<<dim3(2, 8, 16), 1024, 0, stream>>>(
        xr, T4q, DHc, WT, (long long)Dc * 4096, DHc, a, (long long)Tc * 1024, Dc,
        nullptr, DHc, 4096, 4096, 1024, nullptr, nullptr);
    // 5+6) FUSED: t_z = relu(a.DyT^T)*invRoPE(xr) . ET^T — yb eliminated
    gemm56<<<dim3(32, 1, 8), 1024, 0, stream>>>(a, DyT, xr, ET, t, cosT, sinT);
    // 7) v = LN(v + LN(sum_z t_z))
    fuse_ln8<<<Bc * Tc, 256, 0, stream>>>(v, t);
  }

  // out = v . RT^T: [4096 x 256] fp32, K=256 — NW=16, KU=2
  gemm_f16<4, false, false, 16, 2, false><<<dim3(2, 32, 1), 1024, 0, stream>>>(
      v, 0, 0, RT, 0, 0, out, 0, 0, nullptr, Dc, Dc, Dc, Vc, nullptr, nullptr);
}

// Round 25
// 693.917 us; speedup vs baseline: 1.1701x; 1.1701x over previous
//
#include <hip/hip_runtime.h>
#include <cstdint>

namespace {

typedef _Float16 f16_t;
typedef _Float16 f16x8 __attribute__((ext_vector_type(8)));
typedef _Float16 f16x4 __attribute__((ext_vector_type(4)));
typedef float    f32x4 __attribute__((ext_vector_type(4)));
typedef float    f32x16 __attribute__((ext_vector_type(16)));

constexpr int Bc = 4, Tc = 1024, Hc = 4, Dc = 256, DHc = 1024, Lc = 6, Vc = 256;
constexpr int HALFc = 512;
constexpr float EPS = 1e-5f;
constexpr long long T4q  = (long long)Tc * 4096;      // 4M (row stride of xr/y per b)
constexpr long long TDq  = (long long)Tc * Dc;        // 256K
constexpr long long HDDq = (long long)DHc * Dc;       // 256K
constexpr long long TBUFq = (long long)Bc * Tc * Dc;  // 1M (split-K slice)

// Interleaved-pair permutation of the Dh axis: e -> 2*(e%512) + (e/512),
// applied within each head's 1024-block. RoPE pairs (e, e+512) become
// adjacent columns (2j, 2j+1): RoPE (and its inverse) act on adjacent lanes
// of the MFMA C/D fragment via __shfl_xor(.,1). Exact: the he axis is only
// contracted / elementwise / produced from identically-permuted weight rows.
__device__ __forceinline__ int pe_perm(int v) {
  return (v & ~1023) | ((v & 511) << 1) | ((v >> 9) & 1);
}

__device__ __forceinline__ void gload16(const void* g, void* l) {
  __builtin_amdgcn_global_load_lds((const __attribute__((address_space(1))) void*)g,
                                   (__attribute__((address_space(3))) void*)l, 16, 0, 0);
}

// LDS 16B-slot swizzle (r16): slot(k,r) = (k>>3) ^ (r&7) ^ ((r>>3)&7).
// Coalesced k-major staging (column-fastest lanes) + free ds_writes +
// conflict-free ds_read_b128.

// k-major operand staging: P is [K][ld], tile cols c0..c0+127. NW=4/8:
// 16 consecutive lanes read one k-row's 128 cols (contiguous 256B).
// NW=16: thread = (col-group, k-pair, j-half), f16x4 loads (128B per
// 16 lanes); bank: slot spreads 8 values x 4 kp&3 -> 32 banks, 2-way.
template<int NW>
__device__ __forceinline__ void stage_kmaj(const f16_t* __restrict__ P, int k0,
                                           int ld, int c0, f16_t* S, int tid) {
  if constexpr (NW == 16) {
    const int cg = tid & 15;          // col group (8 cols)
    const int kp = (tid >> 4) & 31;   // k-pair
    const int jh = (tid >> 9) * 4;    // j half: 0 or 4
    const int k  = kp * 2;
    const f16x4 r0 = *(const f16x4*)(P + (size_t)(k0 + k) * ld + c0 + cg * 8 + jh);
    const f16x4 r1 = *(const f16x4*)(P + (size_t)(k0 + k + 1) * ld + c0 + cg * 8 + jh);
    #pragma unroll
    for (int j = 0; j < 4; ++j) {
      const int n = cg * 8 + jh + j;
      union { f16_t h[2]; unsigned int u; } pk;
      pk.h[0] = r0[j]; pk.h[1] = r1[j];
      ((unsigned int*)S)[n * 32 + ((((kp >> 2) ^ (n & 7) ^ ((n >> 3) & 7)) & 7) << 2)
                         + (kp & 3)] = pk.u;
    }
  } else {
    const int cg  = tid & 15;        // col group (8 cols)
    const int kpb = tid >> 4;        // k-pair base
    constexpr int NP = (NW == 4) ? 2 : 1;
    #pragma unroll
    for (int p = 0; p < NP; ++p) {
      const int kp = p * 16 + kpb;
      const int k  = kp * 2;
      const f16x8 r0 = *(const f16x8*)(P + (size_t)(k0 + k) * ld + c0 + cg * 8);
      const f16x8 r1 = *(const f16x8*)(P + (size_t)(k0 + k + 1) * ld + c0 + cg * 8);
      #pragma unroll
      for (int j = 0; j < 8; ++j) {
        const int n = cg * 8 + j;
        union { f16_t h[2]; unsigned int u; } pk;
        pk.h[0] = r0[j]; pk.h[1] = r1[j];
        ((unsigned int*)S)[n * 32 + ((((kp >> 2) ^ (n & 7) ^ ((n >> 3) & 7)) & 7) << 2)
                           + (kp & 3)] = pk.u;
      }
    }
  }
}

// ---------------------------------------------------------------------------
// MFMA f16 GEMM. 128x128 tile, BK=64, v_mfma_f32_32x32x16_f16, 1-phase
// single-buffer, KU = K-unroll, GRPZ = reuse-aware z-grouping (r22 win:
// each z-slice's blocks co-located on <=2 XCDs so shared operand panels
// stay L2-resident). r25 = r23 verbatim (best-known 694.6us) — r24's
// gemm5+6 fusion REGRESSED (65us/dispatch, MfmaUtil 9.6%: fusion quartered
// per-barrier MFMA work and serialized stage1->stage2 at 1 block/CU).
// Lesson: traffic cuts only pay when they don't reduce per-barrier MFMA
// work or TLP.
// NW=4 -> 2x2 waves of 64x64 (acc [2][2]); NW=8 -> 2x4 of 64x32 ([2][1]);
// NW=16 -> 4x4 of 32x32 ([1][1]).
// Session ledger: GRPZ win (r22, -53); f16 t-slices win (r20, -23);
// coalesced staging + extended swizzle win (r16, -49); NW=8 win (r7, -106);
// NW=16 on 1-blk/CU win (r23, -14); KU=2 null (r21); XCD chunk-swizzle null
// (r18); transposed epilogue REGRESSED (r17); MFMA shape neutral (r14);
// prefetch pipelining negative (r5/r6); gemm5+6 fusion negative (r24).
// A/B frag: row/col = lane&31, k = (lane>>5)*8 + j; C/D: col = lane&31,
// row = (reg&3)+8*(reg>>2)+4*(lane>>5) (m74/m101-verified).
// AKMAJ/BKMAJ: operand k-major [K][ld] -> stage_kmaj (coalesced, r16).
// Otherwise k-contiguous [rows][K] -> global_load_lds, pre-swizzled src.
// Batch: z = zb*4 + zh. When gridDim.z <= 4, zh carries the index — strides
// go in the s?h slots (r9 bug).
// Epilogue: per-lane row-major (r10/r16-verified).
// EPI: 0 = f16; 2 = relu(acc) * invRoPE(aux) -> C (out-of-place; aux shares
//      C geometry); 4 = fp32; 5 = RoPE(relu(acc)) -> f16
// ---------------------------------------------------------------------------
template<int EPI, bool AKMAJ, bool BKMAJ, int NW, int KU, bool GRPZ>
__global__ __launch_bounds__(NW * 64)
void gemm_f16(const f16_t* __restrict__ A, long long sAb, long long sAh,
              const f16_t* __restrict__ B, long long sBb, long long sBh,
              void* __restrict__ Cv, long long sCb, long long sCh,
              const f16_t* __restrict__ aux,
              int K, int lda, int ldb, int ldc,
              const float* __restrict__ cosP, const float* __restrict__ sinP)
{
  constexpr int FN2  = (NW == 4) ? 2 : 1;   // 32-wide N-tiles per wave
  constexpr int MT   = (NW == 16) ? 1 : 2;  // 32-tall M-tiles per wave
  constexpr int WCW  = FN2 * 32;            // wave column width
  constexpr int WRH  = MT * 32;             // wave row height
  constexpr int NTHR = NW * 64;
  constexpr int SP   = 1024 / NTHR;         // staging passes per 128-row tile
  constexpr int RPP  = NTHR / 8;            // rows per staging pass

  __shared__ __align__(16) f16_t As[KU][128 * 64];
  __shared__ __align__(16) f16_t Bs[KU][128 * 64];

  // r22: reuse-aware z-grouping remap (bijective)
  int bx = blockIdx.x, by = blockIdx.y, bz = blockIdx.z;
  if (GRPZ) {
    const int Xd = gridDim.x, Zd = gridDim.z;
    const int f  = blockIdx.x + Xd * (blockIdx.y + gridDim.y * blockIdx.z);
    bz = f % Zd;
    const int rem = f / Zd;
    bx = rem % Xd;
    by = rem / Xd;
  }

  const int zb = bz >> 2, zh = bz & 3;
  A += zb * sAb + zh * sAh;
  B += zb * sBb + zh * sBh;
  const long long Coff = zb * sCb + zh * sCh;

  const int tid  = threadIdx.x;
  const int lane = tid & 63;
  const int wave = tid >> 6;
  const int wr = (NW == 4) ? (wave >> 1) : (wave >> 2);
  const int wc = (NW == 4) ? (wave & 1)  : (wave & 3);
  const int m0 = by * 128, n0 = bx * 128;

  const int lrow  = tid >> 3;   // row within staging pass
  const int lslot = tid & 7;    // 16B slot in 128B row

  f32x16 acc[MT][FN2] = {};

  for (int k0 = 0; k0 < K; k0 += KU * 64) {
    // ---- stage KU tiles (all async loads in flight before one drain) ----
    #pragma unroll
    for (int u = 0; u < KU; ++u) {
      const int ku = k0 + u * 64;
      if (!AKMAJ) {
        #pragma unroll
        for (int c = 0; c < SP; ++c) {
          const int row  = c * RPP + lrow;
          const int scol = ((lslot ^ (row & 7) ^ ((row >> 3) & 7)) << 3);
          gload16(A + (size_t)(m0 + row) * lda + ku + scol, &As[u][(c * NTHR + tid) * 8]);
        }
      } else {
        stage_kmaj<NW>(A, ku, lda, m0, As[u], tid);
      }
      if (!BKMAJ) {
        #pragma unroll
        for (int c = 0; c < SP; ++c) {
          const int row  = c * RPP + lrow;
          const int scol = ((lslot ^ (row & 7) ^ ((row >> 3) & 7)) << 3);
          gload16(B + (size_t)(n0 + row) * ldb + ku + scol, &Bs[u][(c * NTHR + tid) * 8]);
        }
      } else {
        stage_kmaj<NW>(B, ku, ldb, n0, Bs[u], tid);
      }
    }
    __syncthreads();

    // ---- compute KU tiles; 4 k-chunks of 16 each ----
    #pragma unroll
    for (int u = 0; u < KU; ++u) {
      #pragma unroll
      for (int kc = 0; kc < 4; ++kc) {
        f16x8 af[MT], bf[FN2];
        #pragma unroll
        for (int m = 0; m < MT; ++m) {
          const int r  = wr * WRH + m * 32 + (lane & 31);
          const int sl = (kc * 2 + (lane >> 5)) ^ (r & 7) ^ ((r >> 3) & 7);
          af[m] = *(const f16x8*)(&As[u][r * 64 + sl * 8]);
        }
        #pragma unroll
        for (int n = 0; n < FN2; ++n) {
          const int r  = wc * WCW + n * 32 + (lane & 31);
          const int sl = (kc * 2 + (lane >> 5)) ^ (r & 7) ^ ((r >> 3) & 7);
          bf[n] = *(const f16x8*)(&Bs[u][r * 64 + sl * 8]);
        }
        #pragma unroll
        for (int m = 0; m < MT; ++m)
          #pragma unroll
          for (int n = 0; n < FN2; ++n)
            acc[m][n] = __builtin_amdgcn_mfma_f32_32x32x16_f16(af[m], bf[n], acc[m][n], 0, 0, 0);
      }
    }
    __syncthreads();
  }

  // ---- epilogue (per-lane). C/D: col=lane&31, row=(reg&3)+8*(reg>>2)+4*(lane>>5)
  const int rbase = 4 * (lane >> 5);
  if (EPI == 4) {
    float* C = (float*)Cv + Coff;
    #pragma unroll
    for (int m = 0; m < MT; ++m)
      #pragma unroll
      for (int n = 0; n < FN2; ++n) {
        const int gcol = n0 + wc * WCW + n * 32 + (lane & 31);
        #pragma unroll
        for (int reg = 0; reg < 16; ++reg) {
          const int grow = m0 + wr * WRH + m * 32 + (reg & 3) + 8 * (reg >> 2) + rbase;
          C[(long long)grow * ldc + gcol] = acc[m][n][reg];
        }
      }
  } else if (EPI == 5) {
    // xr = RoPE(relu(acc)); interleaved pair cols -> partner in adjacent lane
    f16_t* C = (f16_t*)Cv + Coff;
    #pragma unroll
    for (int m = 0; m < MT; ++m)
      #pragma unroll
      for (int n = 0; n < FN2; ++n) {
        const int gcol = n0 + wc * WCW + n * 32 + (lane & 31);
        const int jj   = (gcol & 1023) >> 1;
        const float sg = (gcol & 1) ? 1.0f : -1.0f;
        #pragma unroll
        for (int reg = 0; reg < 16; ++reg) {
          const int grow = m0 + wr * WRH + m * 32 + (reg & 3) + 8 * (reg >> 2) + rbase;
          const int tt   = grow & (Tc - 1);
          const float val  = fmaxf(acc[m][n][reg], 0.0f);
          const float part = __shfl_xor(val, 1);
          const float c = cosP[tt * HALFc + jj];
          const float s = sinP[tt * HALFc + jj];
          C[(long long)grow * ldc + gcol] = (f16_t)(val * c + part * s * sg);
        }
      }
  } else if (EPI == 2) {
    // y = relu(acc) * x, x = invRoPE(aux) (aux = xr, out-of-place):
    // even: x0 = xr0*c + xr1*s ; odd: x1 = xr1*c - xr0*s (partner via shfl).
    f16_t* C = (f16_t*)Cv + Coff;
    const f16_t* X = aux + Coff;
    #pragma unroll
    for (int m = 0; m < MT; ++m)
      #pragma unroll
      for (int n = 0; n < FN2; ++n) {
        const int gcol = n0 + wc * WCW + n * 32 + (lane & 31);
        const int jj   = (gcol & 1023) >> 1;
        const float sg = (gcol & 1) ? 1.0f : -1.0f;
        #pragma unroll
        for (int reg = 0; reg < 16; ++reg) {
          const int grow = m0 + wr * WRH + m * 32 + (reg & 3) + 8 * (reg >> 2) + rbase;
          const int tt   = grow & (Tc - 1);
          const long long off = (long long)grow * ldc + gcol;
          const float xrv  = (float)X[off];
          const float part = __shfl_xor(xrv, 1);
          const float c = cosP[tt * HALFc + jj];
          const float s = sinP[tt * HALFc + jj];
          const float xv = xrv * c - part * s * sg;
          C[off] = (f16_t)(fmaxf(acc[m][n][reg], 0.0f) * xv);
        }
      }
  } else {
    f16_t* C = (f16_t*)Cv + Coff;
    #pragma unroll
    for (int m = 0; m < MT; ++m)
      #pragma unroll
      for (int n = 0; n < FN2; ++n) {
        const int gcol = n0 + wc * WCW + n * 32 + (lane & 31);
        #pragma unroll
        for (int reg = 0; reg < 16; ++reg) {
          const int grow = m0 + wr * WRH + m * 32 + (reg & 3) + 8 * (reg >> 2) + rbase;
          C[(long long)grow * ldc + gcol] = (f16_t)acc[m][n][reg];
        }
      }
  }
}

// fp32 [R][C] -> f16 [C][R], batched over z. permR/permC apply the
// interleaved-pair permutation to the output row / column index.
__global__ __launch_bounds__(256)
void transpose_f32_f16(const float* __restrict__ in, f16_t* __restrict__ out,
                       int R, int C, long long sIn, long long sOut,
                       int permR, int permC)
{
  __shared__ float tile[32][33];
  in  += (long long)blockIdx.z * sIn;
  out += (long long)blockIdx.z * sOut;
  const int c0 = blockIdx.x * 32, r0 = blockIdx.y * 32;
  const int tx = threadIdx.x & 31, ty = threadIdx.x >> 5;
  #pragma unroll
  for (int i = 0; i < 32; i += 8)
    tile[ty + i][tx] = in[(long long)(r0 + ty + i) * C + (c0 + tx)];
  __syncthreads();
  #pragma unroll
  for (int i = 0; i < 32; i += 8) {
    int ro = c0 + ty + i;
    int co = r0 + tx;
    if (permR) ro = pe_perm(ro);
    if (permC) co = pe_perm(co);
    out[(long long)ro * R + co] = (f16_t)tile[tx][ty + i];
  }
}

// cos/sin[t][j] = cos/sin(t * 10000^(-j/512)), j in [0,512)
__global__ __launch_bounds__(256)
void init_tables(float* __restrict__ cosT, float* __restrict__ sinT)
{
  const int i = blockIdx.x * 256 + threadIdx.x;  // < T*512
  const int j = i & (HALFc - 1);
  const int t = i >> 9;
  const float inv = expf(-(float)j * (9.210340371976184f / 512.0f));  // ln(1e4)/512
  const float ang = (float)t * inv;
  cosT[i] = cosf(ang);
  sinT[i] = sinf(ang);
}

__device__ __forceinline__ void block_stats(float val, float* red, float& mean, float& inv_std)
{
  float s1 = val, s2 = val * val;
  #pragma unroll
  for (int o = 1; o < 64; o <<= 1) {
    s1 += __shfl_xor(s1, o);
    s2 += __shfl_xor(s2, o);
  }
  const int lane = threadIdx.x & 63;
  const int w = threadIdx.x >> 6;
  if (lane == 0) { red[w * 2] = s1; red[w * 2 + 1] = s2; }
  __syncthreads();
  s1 = red[0] + red[2] + red[4] + red[6];
  s2 = red[1] + red[3] + red[5] + red[7];
  mean = s1 * (1.0f / Dc);
  const float var = s2 * (1.0f / Dc) - mean * mean;
  inv_std = 1.0f / sqrtf(var + EPS);
  __syncthreads();
}

__global__ __launch_bounds__(256)
void embed_ln(const int* __restrict__ tokens, const float* __restrict__ emb,
              f16_t* __restrict__ v)
{
  __shared__ float red[8];
  const int row = blockIdx.x;
  const int d = threadIdx.x;
  const float val = emb[(long long)tokens[row] * Dc + d];
  float m, is;
  block_stats(val, red, m, is);
  v[(long long)row * Dc + d] = (f16_t)((val - m) * is);
}

// v = LN(v + LN(sum_{z<4} t_z)); t split-K slices f16 (r20)
__global__ __launch_bounds__(256)
void fuse_ln4(f16_t* __restrict__ v, const f16_t* __restrict__ t)
{
  __shared__ float red[8];
  const long long row = blockIdx.x;
  const int d = threadIdx.x;
  const long long off = row * Dc + d;
  const float tv = (float)t[off] + (float)t[off + TBUFq]
                 + (float)t[off + 2 * TBUFq] + (float)t[off + 3 * TBUFq];
  float m1, is1;
  block_stats(tv, red, m1, is1);
  const float u = (tv - m1) * is1;
  const float wv = (float)v[off] + u;
  float m2, is2;
  block_stats(wv, red, m2, is2);
  v[off] = (f16_t)((wv - m2) * is2);
}

}  // anonymous namespace

extern "C" void kernel_launch(void* const* d_in, const int* in_sizes, int n_in,
                              void* d_out, int out_size, void* d_ws, size_t ws_size,
                              hipStream_t stream)
{
  (void)in_sizes; (void)n_in; (void)out_size; (void)ws_size;
  const int*   tokens  = (const int*)d_in[0];
  const float* emb_w   = (const float*)d_in[1];
  const float* E       = (const float*)d_in[2];
  const float* Dx      = (const float*)d_in[3];
  const float* Dy      = (const float*)d_in[4];
  const float* readout = (const float*)d_in[5];
  float* out = (float*)d_out;

  // Workspace carve-up (~100 MB)
  char* w = (char*)d_ws;
  auto carve = [&](size_t bytes) { char* p = w; w += (bytes + 255) & ~(size_t)255; return p; };
  float* cosT = (float*)carve((size_t)Tc * HALFc * 4);        // 2 MB
  float* sinT = (float*)carve((size_t)Tc * HALFc * 4);        // 2 MB
  f16_t* v    = (f16_t*)carve((size_t)Bc * Tc * Dc * 2);      // 2 MB
  f16_t* xr   = (f16_t*)carve((size_t)Bc * Tc * 4096 * 2);    // 32 MB [B*T][H*Dh]
  f16_t* yb   = (f16_t*)carve((size_t)Bc * Tc * 4096 * 2);    // 32 MB [B*T][H*Dh] (y)
  f16_t* WT   = (f16_t*)carve((size_t)Bc * Dc * 4096 * 2);    // 8 MB [B][D][H*Dh]
  f16_t* a    = (f16_t*)carve((size_t)Bc * Tc * Hc * Dc * 2); // 8 MB [B*T][H*D]
  f16_t* t    = (f16_t*)carve((size_t)4 * TBUFq * 2);         // 8 MB (f16 split-K slices)
  f16_t* DxT  = (f16_t*)carve((size_t)Hc * DHc * Dc * 2);     // 2 MB [H*Dh][D] (perm rows)
  f16_t* DyT  = (f16_t*)carve((size_t)Hc * DHc * Dc * 2);     // 2 MB (perm rows)
  f16_t* ET   = (f16_t*)carve((size_t)Dc * Hc * DHc * 2);     // 2 MB [D][H*Dh] (perm cols)
  f16_t* RT   = (f16_t*)carve((size_t)Vc * Dc * 2);           // 128 KB

  // One-time prep (weights carry the interleaved-pair he permutation)
  transpose_f32_f16<<<dim3(32, 8, Hc), 256, 0, stream>>>(Dx, DxT, Dc, DHc, HDDq, HDDq, 1, 0);
  transpose_f32_f16<<<dim3(32, 8, Hc), 256, 0, stream>>>(Dy, DyT, Dc, DHc, HDDq, HDDq, 1, 0);
  transpose_f32_f16<<<dim3(8, 128, 1), 256, 0, stream>>>(E, ET, 4096, Dc, 0, 0, 0, 1);
  transpose_f32_f16<<<dim3(8, 8, 1), 256, 0, stream>>>(readout, RT, Dc, Vc, 0, 0, 0, 0);
  init_tables<<<(Tc * HALFc) / 256, 256, 0, stream>>>(cosT, sinT);
  embed_ln<<<Bc * Tc, 256, 0, stream>>>(tokens, emb_w, v);

  for (int l = 0; l < Lc; ++l) {
    // 1) xr = RoPE(relu(v . DxT^T)): [4096 x 4096], K=256 — 1024 blocks,
    //    NW=8, KU=1, no GRPZ (z=1)
    gemm_f16<5, false, false, 8, 1, false><<<dim3(32, 32, 1), 512, 0, stream>>>(
        v, 0, 0, DxT, 0, 0, xr, 0, 0, nullptr, Dc, Dc, Dc, 4096, cosT, sinT);
    // 3) WT[b] = v_b^T . xr_b (A,B both k-major): [256 x 4096], K=1024, z=4
    //    — NW=16, KU=2, GRPZ; batch strides in the s?h slots (r9 bug)
    gemm_f16<0, true, true, 16, 2, true><<<dim3(32, 2, 4), 1024, 0, stream>>>(
        v, 0, TDq, xr, 0, T4q, WT, 0, (long long)Dc * 4096, nullptr,
        Tc, Dc, 4096, 4096, nullptr, nullptr);
    // 4) a[b,:,h,:] = xr_bh . WT_bh^T: [1024 x 256], K=1024, z=16 — NW=16,
    //    KU=2, GRPZ
    gemm_f16<0, false, false, 16, 2, true><<<dim3(2, 8, 16), 1024, 0, stream>>>(
        xr, T4q, DHc, WT, (long long)Dc * 4096, DHc, a, (long long)Tc * 1024, Dc,
        nullptr, DHc, 4096, 4096, 1024, nullptr, nullptr);
    // 5) yb = relu(a_h . DyT_h^T) * invRoPE(xr): [4096 x 1024], z=4 —
    //    1024 blocks, NW=8, KU=1, GRPZ
    gemm_f16<2, false, false, 8, 1, true><<<dim3(8, 32, 4), 512, 0, stream>>>(
        a, 0, Dc, DyT, 0, HDDq, yb, 0, DHc, xr, Dc, 1024, Dc, 4096, cosT, sinT);
    // 6) t_z = yb_h . ET_h^T: [4096 x 256] f16, K=1024, z=4 — NW=16, KU=2, GRPZ
    gemm_f16<0, false, false, 16, 2, true><<<dim3(2, 32, 4), 1024, 0, stream>>>(
        yb, 0, DHc, ET, 0, DHc, t, 0, TBUFq, nullptr, DHc, 4096, 4096, Dc,
        nullptr, nullptr);
    // 7) v = LN(v + LN(sum_z t_z))
    fuse_ln4<<<Bc * Tc, 256, 0, stream>>>(v, t);
  }

  // out = v . RT^T: [4096 x 256] fp32, K=256 — 64 blocks, NW=16, KU=2
  gemm_f16<4, false, false, 16, 2, false><<<dim3(2, 32, 1), 1024, 0, stream>>>(
      v, 0, 0, RT, 0, 0, out, 0, 0, nullptr, Dc, Dc, Dc, Vc, nullptr, nullptr);
}